// Round 1
// baseline (3504.426 us; speedup 1.0000x reference)
//
#include <hip/hip_runtime.h>
#include <math.h>

#define B_    8
#define N_    5000
#define F_    15
#define NCIN  12
#define NCOUT 8
#define NMOM  3
#define H_    256
#define BINSZ 500
#define NBINS 10
#define KNN   16
#define ENCD  26   // NCIN + (F-1)
#define XRD   34   // ENCD + NCOUT
#define M_TOT (B_*N_)  // 40000

__device__ __forceinline__ float elu_f(float x){ return x > 0.f ? x : expm1f(x); }
__device__ __forceinline__ float selu_f(float x){
    const float scale = 1.0507009873554804934193349852946f;
    const float alpha = 1.6732632423543772848170429916717f;
    return x > 0.f ? scale*x : scale*alpha*expm1f(x);
}
__device__ __forceinline__ float sigmoid_f(float x){ return 1.f/(1.f+expf(-x)); }

// ---------------------------------------------------------------- encode
__global__ void k_encode(const float* __restrict__ X, float* __restrict__ enc){
    int i = blockIdx.x*blockDim.x + threadIdx.x;
    if (i >= M_TOT) return;
    const float* x = X + (size_t)i*F_;
    float* e = enc + (size_t)i*ENCD;
    int id = (int)x[0];
    #pragma unroll
    for (int c = 0; c < NCIN; ++c) e[c] = (c == id) ? 1.f : 0.f;
    #pragma unroll
    for (int f = 1; f < F_; ++f) e[NCIN + f - 1] = x[f];
}

// ---------------------------------------------------------------- tiled fp32 GEMM
// C[M,Nw] = act(A[M,K] @ W[K,Nw] + bias). Requires M%64==0 (40000=625*64), Nw%64==0.
// ACT: 0 none, 1 elu, 2 selu, 3 sigmoid. bias may be nullptr.
template<int ACT>
__global__ __launch_bounds__(256) void k_gemm(const float* __restrict__ A,
        const float* __restrict__ W, const float* __restrict__ bias,
        float* __restrict__ C, int M, int K, int Nw){
    __shared__ float As[16][68];   // [k][m], stride 68 floats = 272B (16B aligned)
    __shared__ float Bs[16][64];
    int tid = threadIdx.x;
    int tx = tid & 15, ty = tid >> 4;
    int m0 = blockIdx.x * 64, n0 = blockIdx.y * 64;
    float acc[4][4] = {};
    for (int k0 = 0; k0 < K; k0 += 16){
        for (int i = tid; i < 64*16; i += 256){
            int m = i >> 4, k = i & 15;
            float v = 0.f;
            if (k0 + k < K) v = A[(size_t)(m0+m)*K + k0 + k];
            As[k][m] = v;
        }
        for (int i = tid; i < 16*64; i += 256){
            int k = i >> 6, n = i & 63;
            float v = 0.f;
            if (k0 + k < K) v = W[(size_t)(k0+k)*Nw + n0 + n];
            Bs[k][n] = v;
        }
        __syncthreads();
        #pragma unroll
        for (int k = 0; k < 16; ++k){
            float4 a = *(const float4*)&As[k][ty*4];
            float4 b = *(const float4*)&Bs[k][tx*4];
            float av[4] = {a.x,a.y,a.z,a.w};
            float bv[4] = {b.x,b.y,b.z,b.w};
            #pragma unroll
            for (int i2 = 0; i2 < 4; ++i2)
                #pragma unroll
                for (int j = 0; j < 4; ++j)
                    acc[i2][j] += av[i2]*bv[j];
        }
        __syncthreads();
    }
    #pragma unroll
    for (int i2 = 0; i2 < 4; ++i2){
        int m = m0 + ty*4 + i2;
        float o[4];
        #pragma unroll
        for (int j = 0; j < 4; ++j){
            float v = acc[i2][j];
            if (bias) v += bias[n0 + tx*4 + j];
            if (ACT == 1) v = elu_f(v);
            else if (ACT == 2) v = selu_f(v);
            else if (ACT == 3) v = sigmoid_f(v);
            o[j] = v;
        }
        *(float4*)&C[(size_t)m*Nw + n0 + tx*4] = *(float4*)o;
    }
}

// ---------------------------------------------------------------- small-N GEMM (Nw=8 or 3)
__global__ void k_gemm_small(const float* __restrict__ A, const float* __restrict__ W,
        const float* __restrict__ bias, float* __restrict__ C, int M, int K, int Nw){
    int t = blockIdx.x*blockDim.x + threadIdx.x;
    if (t >= M*Nw) return;
    int m = t / Nw, c = t % Nw;
    const float* a = A + (size_t)m*K;
    float acc = 0.f;
    for (int k = 0; k < K; ++k) acc += a[k] * W[k*Nw + c];
    C[t] = acc + bias[c];
}

// ---------------------------------------------------------------- LSH bin assignment
__global__ void k_bins(const float* __restrict__ xd, const float* __restrict__ R,
                       int* __restrict__ bin_idx){
    int i = blockIdx.x*blockDim.x + threadIdx.x;
    if (i >= M_TOT) return;
    const float* p = xd + (size_t)i*H_;
    float mul[NBINS/2] = {0,0,0,0,0};
    for (int k = 0; k < H_; ++k){
        float x = p[k];
        const float* r = R + k*100;           // R is [256,100], use cols 0..4
        #pragma unroll
        for (int j = 0; j < NBINS/2; ++j) mul[j] += x * r[j];
    }
    float best = mul[0]; int bi = 0;
    #pragma unroll
    for (int j = 1; j < NBINS/2; ++j) if (mul[j] > best){ best = mul[j]; bi = j; }
    #pragma unroll
    for (int j = 0; j < NBINS/2; ++j){ float v = -mul[j]; if (v > best){ best = v; bi = NBINS/2 + j; } }
    bin_idx[i] = bi;
}

// ---------------------------------------------------------------- stable counting sort (per batch)
// replicates jnp.argsort(bin_idx) (stable): order[pos] = node
__global__ __launch_bounds__(256) void k_sort(const int* __restrict__ bin_idx,
                                              int* __restrict__ order){
    int b = blockIdx.x;
    const int* bi = bin_idx + b*N_;
    int* ord = order + b*N_;
    __shared__ int cnt[256][NBINS];
    __shared__ int binoff[NBINS];
    int t = threadIdx.x;
    const int CH = (N_ + 255)/256;  // 20
    int lo = t*CH, hi = lo+CH < N_ ? lo+CH : N_;
    for (int j = 0; j < NBINS; ++j) cnt[t][j] = 0;
    for (int n = lo; n < hi; ++n) cnt[t][bi[n]]++;
    __syncthreads();
    if (t < NBINS){
        int run = 0;
        for (int q = 0; q < 256; ++q){ int v = cnt[q][t]; cnt[q][t] = run; run += v; }
        binoff[t] = run;
    }
    __syncthreads();
    if (t == 0){
        int run = 0;
        for (int j = 0; j < NBINS; ++j){ int v = binoff[j]; binoff[j] = run; run += v; }
    }
    __syncthreads();
    for (int n = lo; n < hi; ++n){
        int v = bi[n];
        int pos = binoff[v] + cnt[t][v]++;
        ord[pos] = n;
    }
}

// ---------------------------------------------------------------- squared norms
__global__ void k_sq(const float* __restrict__ xd, float* __restrict__ sq){
    int i = blockIdx.x*blockDim.x + threadIdx.x;
    if (i >= M_TOT) return;
    const float4* p = (const float4*)(xd + (size_t)i*H_);
    float s = 0.f;
    for (int k = 0; k < H_/4; ++k){ float4 v = p[k]; s += v.x*v.x + v.y*v.y + v.z*v.z + v.w*v.w; }
    sq[i] = s;
}

// ---------------------------------------------------------------- kNN: one block per row
// computes dm row (500 candidates), selects top-16 (ties -> lowest index), writes
// neighbor ids (within-batch), vals, and norm = (sum vals + 1e-6)^-0.5
__global__ __launch_bounds__(256) void k_knn(const float* __restrict__ xd,
        const float* __restrict__ sq, const int* __restrict__ order,
        int* __restrict__ nbr_idx, float* __restrict__ nbr_val,
        float* __restrict__ nrm){
    int blk = blockIdx.x;            // b*N_ + pos
    int b = blk / N_;
    int pos = blk % N_;
    int bin = pos / BINSZ;
    int r = pos % BINSZ;
    const int* ord = order + b*N_ + bin*BINSZ;
    int t = threadIdx.x;
    __shared__ float p[H_];
    __shared__ float dmv[BINSZ];
    __shared__ int ordl[BINSZ];
    __shared__ unsigned long long red[256];
    __shared__ float outv[KNN];
    __shared__ int outi[KNN];
    int node_i = ord[r];
    p[t] = xd[((size_t)b*N_ + node_i)*H_ + t];
    for (int c = t; c < BINSZ; c += 256) ordl[c] = ord[c];
    __syncthreads();
    float sqi = sq[b*N_ + node_i];
    for (int c = t; c < BINSZ; c += 256){
        int nj = ordl[c];
        const float4* q = (const float4*)(xd + ((size_t)b*N_ + nj)*H_);
        const float4* pp = (const float4*)p;
        float s0=0.f,s1=0.f,s2=0.f,s3=0.f;
        #pragma unroll 8
        for (int k = 0; k < H_/4; ++k){
            float4 a = pp[k]; float4 v = q[k];
            s0 += a.x*v.x; s1 += a.y*v.y; s2 += a.z*v.z; s3 += a.w*v.w;
        }
        float dot = (s0+s1)+(s2+s3);
        float d2 = sqi - 2.f*dot + sq[b*N_ + nj];
        dmv[c] = expf(-0.1f * sqrtf(fmaxf(d2, 1e-6f)));
    }
    __syncthreads();
    for (int rr = 0; rr < KNN; ++rr){
        unsigned long long key = 0ull;
        for (int c = t; c < BINSZ; c += 256){
            unsigned int fb = __float_as_uint(dmv[c]);       // dm > 0 -> monotone bits
            unsigned long long k2 = ((unsigned long long)fb << 32) | (unsigned)(BINSZ - c);
            if (k2 > key) key = k2;
        }
        red[t] = key;
        __syncthreads();
        for (int s = 128; s > 0; s >>= 1){
            if (t < s){ unsigned long long o = red[t+s]; if (o > red[t]) red[t] = o; }
            __syncthreads();
        }
        if (t == 0){
            unsigned long long k2 = red[0];
            int c = BINSZ - (int)(k2 & 0xffffffffu);
            outv[rr] = __uint_as_float((unsigned)(k2 >> 32));
            outi[rr] = c;
            dmv[c] = 0.f;   // bits 0: can never win again
        }
        __syncthreads();
    }
    if (t < KNN){
        int c = outi[t];
        nbr_idx[((size_t)b*N_ + node_i)*KNN + t] = ordl[c];
        nbr_val[((size_t)b*N_ + node_i)*KNN + t] = outv[t];
    }
    if (t == 0){
        float deg = 0.f;
        for (int k = 0; k < KNN; ++k) deg += outv[k];   // vals > 0, abs redundant
        nrm[b*N_ + node_i] = 1.0f / sqrtf(deg + 1e-6f);
    }
}

// ---------------------------------------------------------------- GHConv combine
// out = selu(gate * (norm_i * sum_k val_k*norm_dst*hom[dst]) + (1-gate)*het)
__global__ __launch_bounds__(256) void k_ghconv(const float* __restrict__ gate,
        const float* __restrict__ het, const float* __restrict__ hom,
        const int* __restrict__ nbr_idx, const float* __restrict__ nbr_val,
        const float* __restrict__ nrm, float* __restrict__ out){
    int node = blockIdx.x;           // b*N_ + n
    int b = node / N_;
    int t = threadIdx.x;
    __shared__ int nid[KNN];
    __shared__ float nv[KNN];
    if (t < KNN){
        int d = nbr_idx[(size_t)node*KNN + t];
        nid[t] = d;
        nv[t] = nbr_val[(size_t)node*KNN + t] * nrm[b*N_ + d];
    }
    __syncthreads();
    float acc = 0.f;
    #pragma unroll
    for (int k = 0; k < KNN; ++k)
        acc += nv[k] * hom[((size_t)b*N_ + nid[k])*H_ + t];
    float ni = nrm[node];
    float g = gate[(size_t)node*H_ + t];
    float v = g * (ni * acc) + (1.f - g) * het[(size_t)node*H_ + t];
    out[(size_t)node*H_ + t] = selu_f(v);
}

// ---------------------------------------------------------------- xr concat
__global__ void k_xr(const float* __restrict__ enc, const float* __restrict__ logits,
                     float* __restrict__ xr){
    int i = blockIdx.x*blockDim.x + threadIdx.x;
    if (i >= M_TOT) return;
    const float* e = enc + (size_t)i*ENCD;
    const float* l = logits + (size_t)i*NCOUT;
    float* x = xr + (size_t)i*XRD;
    #pragma unroll
    for (int j = 0; j < ENCD; ++j) x[j] = e[j];
    #pragma unroll
    for (int j = 0; j < NCOUT; ++j) x[ENCD+j] = l[j];
}

// ----------------------------------------------------------------
extern "C" void kernel_launch(void* const* d_in, const int* in_sizes, int n_in,
                              void* d_out, int out_size, void* d_ws, size_t ws_size,
                              hipStream_t stream){
    const float* X        = (const float*)d_in[0];
    const float* ffn1_w   = (const float*)d_in[1];
    const float* ffn1_b   = (const float*)d_in[2];
    const float* ffn2_w   = (const float*)d_in[3];
    const float* ffn2_b   = (const float*)d_in[4];
    const float* R        = (const float*)d_in[5];
    const float* enc_id_w = (const float*)d_in[6];
    const float* enc_id_b = (const float*)d_in[7];
    const float* wt_id    = (const float*)d_in[8];
    const float* bt_id    = (const float*)d_in[9];
    const float* wh_id    = (const float*)d_in[10];
    const float* theta_id = (const float*)d_in[11];
    const float* dec_id_w = (const float*)d_in[12];
    const float* dec_id_b = (const float*)d_in[13];
    const float* out_id_w = (const float*)d_in[14];
    const float* out_id_b = (const float*)d_in[15];
    const float* enc_reg_w= (const float*)d_in[16];
    const float* enc_reg_b= (const float*)d_in[17];
    const float* wt_reg   = (const float*)d_in[18];
    const float* bt_reg   = (const float*)d_in[19];
    const float* wh_reg   = (const float*)d_in[20];
    const float* theta_reg= (const float*)d_in[21];
    const float* dec_reg_w= (const float*)d_in[22];
    const float* dec_reg_b= (const float*)d_in[23];
    const float* out_reg_w= (const float*)d_in[24];
    const float* out_reg_b= (const float*)d_in[25];

    float* out_logits = (float*)d_out;                     // [B,N,8]
    float* out_mom    = (float*)d_out + (size_t)M_TOT*NCOUT; // [B,N,3]

    // workspace layout (all fp32 except int tail)
    float* ws = (float*)d_ws;
    size_t o = 0;
    float* enc  = ws + o; o += (size_t)M_TOT*ENCD;
    float* bufA = ws + o; o += (size_t)M_TOT*H_;
    float* bufB = ws + o; o += (size_t)M_TOT*H_;
    float* bufC = ws + o; o += (size_t)M_TOT*H_;
    float* bufD = ws + o; o += (size_t)M_TOT*H_;
    float* sq   = ws + o; o += M_TOT;
    float* nrm  = ws + o; o += M_TOT;
    float* xr   = ws + o; o += (size_t)M_TOT*XRD;
    float* nbrv = ws + o; o += (size_t)M_TOT*KNN;
    int* ibase   = (int*)(ws + o);
    int* bin_idx = ibase;
    int* order   = ibase + M_TOT;
    int* nbr_idx = ibase + 2*M_TOT;

    dim3 b256(256);
    int nb = (M_TOT + 255)/256;
    dim3 gg(625, H_/64);   // big-GEMM grid (M=40000, Nw=256)

    // ---- encoding + x_dist
    k_encode<<<nb, b256, 0, stream>>>(X, enc);
    k_gemm<1><<<gg, b256, 0, stream>>>(enc,  ffn1_w, ffn1_b, bufA, M_TOT, ENCD, H_);
    k_gemm<0><<<gg, b256, 0, stream>>>(bufA, ffn2_w, ffn2_b, bufB, M_TOT, H_,   H_); // x_dist -> B

    // ---- graph build
    k_bins<<<nb, b256, 0, stream>>>(bufB, R, bin_idx);
    k_sort<<<B_, b256, 0, stream>>>(bin_idx, order);
    k_sq<<<nb, b256, 0, stream>>>(bufB, sq);
    k_knn<<<M_TOT, b256, 0, stream>>>(bufB, sq, order, nbr_idx, nbrv, nrm);

    // ---- id branch
    k_gemm<2><<<gg, b256, 0, stream>>>(enc,  enc_id_w, enc_id_b, bufA, M_TOT, ENCD, H_); // h0 -> A
    k_gemm<3><<<gg, b256, 0, stream>>>(bufA, wt_id, bt_id,  bufC, M_TOT, H_, H_);        // gate -> C
    k_gemm<0><<<gg, b256, 0, stream>>>(bufA, wh_id, nullptr, bufD, M_TOT, H_, H_);       // het -> D
    k_gemm<0><<<gg, b256, 0, stream>>>(bufA, theta_id, nullptr, bufB, M_TOT, H_, H_);    // hom -> B
    k_ghconv<<<M_TOT, b256, 0, stream>>>(bufC, bufD, bufB, nbr_idx, nbrv, nrm, bufA);    // h1 -> A
    k_gemm<2><<<gg, b256, 0, stream>>>(bufA, dec_id_w, dec_id_b, bufB, M_TOT, H_, H_);   // h2 -> B
    k_gemm_small<<<(M_TOT*NCOUT + 255)/256, b256, 0, stream>>>(bufB, out_id_w, out_id_b,
                                                               out_logits, M_TOT, H_, NCOUT);

    // ---- reg branch
    k_xr<<<nb, b256, 0, stream>>>(enc, out_logits, xr);
    k_gemm<2><<<gg, b256, 0, stream>>>(xr,   enc_reg_w, enc_reg_b, bufA, M_TOT, XRD, H_); // g0 -> A
    k_gemm<3><<<gg, b256, 0, stream>>>(bufA, wt_reg, bt_reg,  bufC, M_TOT, H_, H_);
    k_gemm<0><<<gg, b256, 0, stream>>>(bufA, wh_reg, nullptr, bufD, M_TOT, H_, H_);
    k_gemm<0><<<gg, b256, 0, stream>>>(bufA, theta_reg, nullptr, bufB, M_TOT, H_, H_);
    k_ghconv<<<M_TOT, b256, 0, stream>>>(bufC, bufD, bufB, nbr_idx, nbrv, nrm, bufA);     // g1 -> A
    k_gemm<2><<<gg, b256, 0, stream>>>(bufA, dec_reg_w, dec_reg_b, bufB, M_TOT, H_, H_);  // g2 -> B
    k_gemm_small<<<(M_TOT*NMOM + 255)/256, b256, 0, stream>>>(bufB, out_reg_w, out_reg_b,
                                                              out_mom, M_TOT, H_, NMOM);

    (void)in_sizes; (void)n_in; (void)out_size; (void)ws_size;
}

// Round 2
// 1602.596 us; speedup vs baseline: 2.1867x; 2.1867x over previous
//
#include <hip/hip_runtime.h>
#include <math.h>

#define B_    8
#define N_    5000
#define F_    15
#define NCIN  12
#define NCOUT 8
#define NMOM  3
#define H_    256
#define BINSZ 500
#define NBINS 10
#define KNN   16
#define ENCD  26   // NCIN + (F-1)
#define XRD   34   // ENCD + NCOUT
#define M_TOT (B_*N_)  // 40000

__device__ __forceinline__ float elu_f(float x){ return x > 0.f ? x : expm1f(x); }
__device__ __forceinline__ float selu_f(float x){
    const float scale = 1.0507009873554804934193349852946f;
    const float alpha = 1.6732632423543772848170429916717f;
    return x > 0.f ? scale*x : scale*alpha*expm1f(x);
}
__device__ __forceinline__ float sigmoid_f(float x){ return 1.f/(1.f+expf(-x)); }

// ---------------------------------------------------------------- encode
__global__ void k_encode(const float* __restrict__ X, float* __restrict__ enc){
    int i = blockIdx.x*blockDim.x + threadIdx.x;
    if (i >= M_TOT) return;
    const float* x = X + (size_t)i*F_;
    float* e = enc + (size_t)i*ENCD;
    int id = (int)x[0];
    #pragma unroll
    for (int c = 0; c < NCIN; ++c) e[c] = (c == id) ? 1.f : 0.f;
    #pragma unroll
    for (int f = 1; f < F_; ++f) e[NCIN + f - 1] = x[f];
}

// ---------------------------------------------------------------- tiled fp32 GEMM
// C[M,Nw] = act(A[M,K] @ W[K,Nw] + bias). Requires M%64==0, Nw%64==0.
// ACT: 0 none, 1 elu, 2 selu, 3 sigmoid. bias may be nullptr.
template<int ACT>
__global__ __launch_bounds__(256) void k_gemm(const float* __restrict__ A,
        const float* __restrict__ W, const float* __restrict__ bias,
        float* __restrict__ C, int M, int K, int Nw){
    __shared__ float As[16][68];
    __shared__ float Bs[16][64];
    int tid = threadIdx.x;
    int tx = tid & 15, ty = tid >> 4;
    int m0 = blockIdx.x * 64, n0 = blockIdx.y * 64;
    float acc[4][4] = {};
    for (int k0 = 0; k0 < K; k0 += 16){
        for (int i = tid; i < 64*16; i += 256){
            int m = i >> 4, k = i & 15;
            float v = 0.f;
            if (k0 + k < K) v = A[(size_t)(m0+m)*K + k0 + k];
            As[k][m] = v;
        }
        for (int i = tid; i < 16*64; i += 256){
            int k = i >> 6, n = i & 63;
            float v = 0.f;
            if (k0 + k < K) v = W[(size_t)(k0+k)*Nw + n0 + n];
            Bs[k][n] = v;
        }
        __syncthreads();
        #pragma unroll
        for (int k = 0; k < 16; ++k){
            float4 a = *(const float4*)&As[k][ty*4];
            float4 b = *(const float4*)&Bs[k][tx*4];
            float av[4] = {a.x,a.y,a.z,a.w};
            float bv[4] = {b.x,b.y,b.z,b.w};
            #pragma unroll
            for (int i2 = 0; i2 < 4; ++i2)
                #pragma unroll
                for (int j = 0; j < 4; ++j)
                    acc[i2][j] += av[i2]*bv[j];
        }
        __syncthreads();
    }
    #pragma unroll
    for (int i2 = 0; i2 < 4; ++i2){
        int m = m0 + ty*4 + i2;
        float o[4];
        #pragma unroll
        for (int j = 0; j < 4; ++j){
            float v = acc[i2][j];
            if (bias) v += bias[n0 + tx*4 + j];
            if (ACT == 1) v = elu_f(v);
            else if (ACT == 2) v = selu_f(v);
            else if (ACT == 3) v = sigmoid_f(v);
            o[j] = v;
        }
        *(float4*)&C[(size_t)m*Nw + n0 + tx*4] = *(float4*)o;
    }
}

// ---------------------------------------------------------------- small-N GEMM (Nw=8 or 3)
__global__ void k_gemm_small(const float* __restrict__ A, const float* __restrict__ W,
        const float* __restrict__ bias, float* __restrict__ C, int M, int K, int Nw){
    int t = blockIdx.x*blockDim.x + threadIdx.x;
    if (t >= M*Nw) return;
    int m = t / Nw, c = t % Nw;
    const float* a = A + (size_t)m*K;
    float acc = 0.f;
    for (int k = 0; k < K; ++k) acc += a[k] * W[k*Nw + c];
    C[t] = acc + bias[c];
}

// ---------------------------------------------------------------- LSH bin assignment
__global__ void k_bins(const float* __restrict__ xd, const float* __restrict__ R,
                       int* __restrict__ bin_idx){
    int i = blockIdx.x*blockDim.x + threadIdx.x;
    if (i >= M_TOT) return;
    const float* p = xd + (size_t)i*H_;
    float mul[NBINS/2] = {0,0,0,0,0};
    for (int k = 0; k < H_; ++k){
        float x = p[k];
        const float* r = R + k*100;           // R is [256,100], use cols 0..4
        #pragma unroll
        for (int j = 0; j < NBINS/2; ++j) mul[j] += x * r[j];
    }
    float best = mul[0]; int bi = 0;
    #pragma unroll
    for (int j = 1; j < NBINS/2; ++j) if (mul[j] > best){ best = mul[j]; bi = j; }
    #pragma unroll
    for (int j = 0; j < NBINS/2; ++j){ float v = -mul[j]; if (v > best){ best = v; bi = NBINS/2 + j; } }
    bin_idx[i] = bi;
}

// ---------------------------------------------------------------- stable counting sort (per batch)
__global__ __launch_bounds__(256) void k_sort(const int* __restrict__ bin_idx,
                                              int* __restrict__ order){
    int b = blockIdx.x;
    const int* bi = bin_idx + b*N_;
    int* ord = order + b*N_;
    __shared__ int cnt[256][NBINS];
    __shared__ int binoff[NBINS];
    int t = threadIdx.x;
    const int CH = (N_ + 255)/256;  // 20
    int lo = t*CH, hi = lo+CH < N_ ? lo+CH : N_;
    for (int j = 0; j < NBINS; ++j) cnt[t][j] = 0;
    for (int n = lo; n < hi; ++n) cnt[t][bi[n]]++;
    __syncthreads();
    if (t < NBINS){
        int run = 0;
        for (int q = 0; q < 256; ++q){ int v = cnt[q][t]; cnt[q][t] = run; run += v; }
        binoff[t] = run;
    }
    __syncthreads();
    if (t == 0){
        int run = 0;
        for (int j = 0; j < NBINS; ++j){ int v = binoff[j]; binoff[j] = run; run += v; }
    }
    __syncthreads();
    for (int n = lo; n < hi; ++n){
        int v = bi[n];
        int pos = binoff[v] + cnt[t][v]++;
        ord[pos] = n;
    }
}

// ---------------------------------------------------------------- squared norms
__global__ void k_sq(const float* __restrict__ xd, float* __restrict__ sq){
    int i = blockIdx.x*blockDim.x + threadIdx.x;
    if (i >= M_TOT) return;
    const float4* p = (const float4*)(xd + (size_t)i*H_);
    float s = 0.f;
    for (int k = 0; k < H_/4; ++k){ float4 v = p[k]; s += v.x*v.x + v.y*v.y + v.z*v.z + v.w*v.w; }
    sq[i] = s;
}

// ---------------------------------------------------------------- distance-matrix GEMM
// dm[binlin][r][c] = exp(-0.1*sqrt(max(d2,1e-6))), d2 over gathered bin points.
// grid: (80 binlin, 64 tiles of 64x64 over 500x500)
__global__ __launch_bounds__(256) void k_dist(const float* __restrict__ xd,
        const float* __restrict__ sq, const int* __restrict__ order,
        float* __restrict__ dm){
    int binlin = blockIdx.x;           // b*NBINS + bin
    int b = binlin / NBINS;
    int tr = (blockIdx.y >> 3) * 64;
    int tc = (blockIdx.y & 7) * 64;
    const int* ord = order + b*N_ + (binlin % NBINS)*BINSZ;
    __shared__ int ordr[64], ordc[64];
    __shared__ float sqr[64], sqc[64];
    __shared__ float As[16][68];
    __shared__ float Bs[16][64];
    int tid = threadIdx.x;
    if (tid < 64){
        int rr = tr + tid;
        int node = ord[rr < BINSZ ? rr : 0];
        ordr[tid] = node; sqr[tid] = sq[b*N_ + node];
    } else if (tid < 128){
        int cc = tc + tid - 64;
        int node = ord[cc < BINSZ ? cc : 0];
        ordc[tid-64] = node; sqc[tid-64] = sq[b*N_ + node];
    }
    __syncthreads();
    int tx = tid & 15, ty = tid >> 4;
    float acc[4][4] = {};
    for (int k0 = 0; k0 < H_; k0 += 16){
        for (int i = tid; i < 1024; i += 256){
            int m = i >> 4, k = i & 15;
            As[k][m] = xd[((size_t)b*N_ + ordr[m])*H_ + k0 + k];
        }
        for (int i = tid; i < 1024; i += 256){
            int m = i >> 4, k = i & 15;
            Bs[k][m] = xd[((size_t)b*N_ + ordc[m])*H_ + k0 + k];
        }
        __syncthreads();
        #pragma unroll
        for (int k = 0; k < 16; ++k){
            float4 a = *(const float4*)&As[k][ty*4];
            float4 bv4 = *(const float4*)&Bs[k][tx*4];
            float av[4] = {a.x,a.y,a.z,a.w};
            float bv[4] = {bv4.x,bv4.y,bv4.z,bv4.w};
            #pragma unroll
            for (int i2 = 0; i2 < 4; ++i2)
                #pragma unroll
                for (int j = 0; j < 4; ++j)
                    acc[i2][j] += av[i2]*bv[j];
        }
        __syncthreads();
    }
    #pragma unroll
    for (int i2 = 0; i2 < 4; ++i2){
        int r = tr + ty*4 + i2;
        if (r >= BINSZ) continue;
        #pragma unroll
        for (int j = 0; j < 4; ++j){
            int c = tc + tx*4 + j;
            if (c >= BINSZ) continue;
            float d2 = sqr[ty*4+i2] - 2.f*acc[i2][j] + sqc[tx*4+j];
            dm[((size_t)binlin*BINSZ + r)*BINSZ + c] = expf(-0.1f*sqrtf(fmaxf(d2, 1e-6f)));
        }
    }
}

// ---------------------------------------------------------------- top-16 selection, one wave per row
__global__ __launch_bounds__(256) void k_sel(const float* __restrict__ dm,
        const int* __restrict__ order,
        int* __restrict__ nbr_idx, float* __restrict__ nbr_val,
        float* __restrict__ nrm){
    int g = blockIdx.x*4 + (threadIdx.x >> 6);   // global row 0..39999
    int lane = threadIdx.x & 63;
    int b = g / N_, pos = g % N_;
    int bin = pos / BINSZ, r = pos % BINSZ;
    int binlin = b*NBINS + bin;
    const float* row = dm + ((size_t)binlin*BINSZ + r)*BINSZ;
    unsigned long long key[8];
    #pragma unroll
    for (int s = 0; s < 8; ++s){
        int c = lane + s*64;
        key[s] = 0ull;
        if (c < BINSZ){
            unsigned fb = __float_as_uint(row[c]);   // dm > 0 -> monotone bits
            key[s] = ((unsigned long long)fb << 32) | (unsigned)(BINSZ - c);
        }
    }
    float myv = 0.f; int myc = 0;
    for (int rr = 0; rr < KNN; ++rr){
        unsigned long long k2 = key[0];
        #pragma unroll
        for (int s = 1; s < 8; ++s) if (key[s] > k2) k2 = key[s];
        #pragma unroll
        for (int off = 32; off; off >>= 1){
            unsigned long long o = __shfl_xor(k2, off, 64);
            if (o > k2) k2 = o;
        }
        int c = BINSZ - (int)(k2 & 0xffffffffu);
        float v = __uint_as_float((unsigned)(k2 >> 32));
        if (lane == rr){ myv = v; myc = c; }
        if (lane == (c & 63)) key[c >> 6] = 0ull;   // remove winner
    }
    float deg = 0.f;
    #pragma unroll
    for (int rr = 0; rr < KNN; ++rr) deg += __shfl(myv, rr, 64);
    const int* ord = order + b*N_ + bin*BINSZ;
    int node_i = ord[r];
    if (lane < KNN){
        nbr_idx[((size_t)b*N_ + node_i)*KNN + lane] = ord[myc];
        nbr_val[((size_t)b*N_ + node_i)*KNN + lane] = myv;
    }
    if (lane == 0) nrm[b*N_ + node_i] = 1.f/sqrtf(deg + 1e-6f);
}

// ---------------------------------------------------------------- GHConv combine
__global__ __launch_bounds__(256) void k_ghconv(const float* __restrict__ gate,
        const float* __restrict__ het, const float* __restrict__ hom,
        const int* __restrict__ nbr_idx, const float* __restrict__ nbr_val,
        const float* __restrict__ nrm, float* __restrict__ out){
    int node = blockIdx.x;           // b*N_ + n
    int b = node / N_;
    int t = threadIdx.x;
    __shared__ int nid[KNN];
    __shared__ float nv[KNN];
    if (t < KNN){
        int d = nbr_idx[(size_t)node*KNN + t];
        nid[t] = d;
        nv[t] = nbr_val[(size_t)node*KNN + t] * nrm[b*N_ + d];
    }
    __syncthreads();
    float acc = 0.f;
    #pragma unroll
    for (int k = 0; k < KNN; ++k)
        acc += nv[k] * hom[((size_t)b*N_ + nid[k])*H_ + t];
    float ni = nrm[node];
    float g = gate[(size_t)node*H_ + t];
    float v = g * (ni * acc) + (1.f - g) * het[(size_t)node*H_ + t];
    out[(size_t)node*H_ + t] = selu_f(v);
}

// ---------------------------------------------------------------- xr concat
__global__ void k_xr(const float* __restrict__ enc, const float* __restrict__ logits,
                     float* __restrict__ xr){
    int i = blockIdx.x*blockDim.x + threadIdx.x;
    if (i >= M_TOT) return;
    const float* e = enc + (size_t)i*ENCD;
    const float* l = logits + (size_t)i*NCOUT;
    float* x = xr + (size_t)i*XRD;
    #pragma unroll
    for (int j = 0; j < ENCD; ++j) x[j] = e[j];
    #pragma unroll
    for (int j = 0; j < NCOUT; ++j) x[ENCD+j] = l[j];
}

// ----------------------------------------------------------------
extern "C" void kernel_launch(void* const* d_in, const int* in_sizes, int n_in,
                              void* d_out, int out_size, void* d_ws, size_t ws_size,
                              hipStream_t stream){
    const float* X        = (const float*)d_in[0];
    const float* ffn1_w   = (const float*)d_in[1];
    const float* ffn1_b   = (const float*)d_in[2];
    const float* ffn2_w   = (const float*)d_in[3];
    const float* ffn2_b   = (const float*)d_in[4];
    const float* R        = (const float*)d_in[5];
    const float* enc_id_w = (const float*)d_in[6];
    const float* enc_id_b = (const float*)d_in[7];
    const float* wt_id    = (const float*)d_in[8];
    const float* bt_id    = (const float*)d_in[9];
    const float* wh_id    = (const float*)d_in[10];
    const float* theta_id = (const float*)d_in[11];
    const float* dec_id_w = (const float*)d_in[12];
    const float* dec_id_b = (const float*)d_in[13];
    const float* out_id_w = (const float*)d_in[14];
    const float* out_id_b = (const float*)d_in[15];
    const float* enc_reg_w= (const float*)d_in[16];
    const float* enc_reg_b= (const float*)d_in[17];
    const float* wt_reg   = (const float*)d_in[18];
    const float* bt_reg   = (const float*)d_in[19];
    const float* wh_reg   = (const float*)d_in[20];
    const float* theta_reg= (const float*)d_in[21];
    const float* dec_reg_w= (const float*)d_in[22];
    const float* dec_reg_b= (const float*)d_in[23];
    const float* out_reg_w= (const float*)d_in[24];
    const float* out_reg_b= (const float*)d_in[25];

    float* out_logits = (float*)d_out;                       // [B,N,8]
    float* out_mom    = (float*)d_out + (size_t)M_TOT*NCOUT; // [B,N,3]

    float* ws = (float*)d_ws;
    size_t o = 0;
    float* enc  = ws + o; o += (size_t)M_TOT*ENCD;
    float* bufA = ws + o; o += (size_t)M_TOT*H_;
    float* bufB = ws + o; o += (size_t)M_TOT*H_;
    float* bufC = ws + o; o += (size_t)M_TOT*H_;   // dm aliases bufC+bufD (80 MB)
    float* bufD = ws + o; o += (size_t)M_TOT*H_;
    float* sq   = ws + o; o += M_TOT;
    float* nrm  = ws + o; o += M_TOT;
    float* xr   = ws + o; o += (size_t)M_TOT*XRD;
    float* nbrv = ws + o; o += (size_t)M_TOT*KNN;
    int* ibase   = (int*)(ws + o);
    int* bin_idx = ibase;
    int* order   = ibase + M_TOT;
    int* nbr_idx = ibase + 2*M_TOT;
    float* dm = bufC;   // 8*10*500*500 floats = 80 MB, free until gate GEMM

    dim3 b256(256);
    int nb = (M_TOT + 255)/256;
    dim3 gg(625, H_/64);

    // ---- encoding + x_dist
    k_encode<<<nb, b256, 0, stream>>>(X, enc);
    k_gemm<1><<<gg, b256, 0, stream>>>(enc,  ffn1_w, ffn1_b, bufA, M_TOT, ENCD, H_);
    k_gemm<0><<<gg, b256, 0, stream>>>(bufA, ffn2_w, ffn2_b, bufB, M_TOT, H_,   H_); // x_dist -> B

    // ---- graph build
    k_bins<<<nb, b256, 0, stream>>>(bufB, R, bin_idx);
    k_sort<<<B_, b256, 0, stream>>>(bin_idx, order);
    k_sq<<<nb, b256, 0, stream>>>(bufB, sq);
    k_dist<<<dim3(B_*NBINS, 64), b256, 0, stream>>>(bufB, sq, order, dm);
    k_sel<<<M_TOT/4, b256, 0, stream>>>(dm, order, nbr_idx, nbrv, nrm);

    // ---- id branch
    k_gemm<2><<<gg, b256, 0, stream>>>(enc,  enc_id_w, enc_id_b, bufA, M_TOT, ENCD, H_); // h0 -> A
    k_gemm<3><<<gg, b256, 0, stream>>>(bufA, wt_id, bt_id,  bufC, M_TOT, H_, H_);        // gate -> C
    k_gemm<0><<<gg, b256, 0, stream>>>(bufA, wh_id, nullptr, bufD, M_TOT, H_, H_);       // het -> D
    k_gemm<0><<<gg, b256, 0, stream>>>(bufA, theta_id, nullptr, bufB, M_TOT, H_, H_);    // hom -> B
    k_ghconv<<<M_TOT, b256, 0, stream>>>(bufC, bufD, bufB, nbr_idx, nbrv, nrm, bufA);    // h1 -> A
    k_gemm<2><<<gg, b256, 0, stream>>>(bufA, dec_id_w, dec_id_b, bufB, M_TOT, H_, H_);   // h2 -> B
    k_gemm_small<<<(M_TOT*NCOUT + 255)/256, b256, 0, stream>>>(bufB, out_id_w, out_id_b,
                                                               out_logits, M_TOT, H_, NCOUT);

    // ---- reg branch
    k_xr<<<nb, b256, 0, stream>>>(enc, out_logits, xr);
    k_gemm<2><<<gg, b256, 0, stream>>>(xr,   enc_reg_w, enc_reg_b, bufA, M_TOT, XRD, H_); // g0 -> A
    k_gemm<3><<<gg, b256, 0, stream>>>(bufA, wt_reg, bt_reg,  bufC, M_TOT, H_, H_);
    k_gemm<0><<<gg, b256, 0, stream>>>(bufA, wh_reg, nullptr, bufD, M_TOT, H_, H_);
    k_gemm<0><<<gg, b256, 0, stream>>>(bufA, theta_reg, nullptr, bufB, M_TOT, H_, H_);
    k_ghconv<<<M_TOT, b256, 0, stream>>>(bufC, bufD, bufB, nbr_idx, nbrv, nrm, bufA);     // g1 -> A
    k_gemm<2><<<gg, b256, 0, stream>>>(bufA, dec_reg_w, dec_reg_b, bufB, M_TOT, H_, H_);  // g2 -> B
    k_gemm_small<<<(M_TOT*NMOM + 255)/256, b256, 0, stream>>>(bufB, out_reg_w, out_reg_b,
                                                              out_mom, M_TOT, H_, NMOM);

    (void)in_sizes; (void)n_in; (void)out_size; (void)ws_size;
}

// Round 3
// 922.491 us; speedup vs baseline: 3.7989x; 1.7372x over previous
//
#include <hip/hip_runtime.h>
#include <math.h>

#define B_    8
#define N_    5000
#define F_    15
#define NCIN  12
#define NCOUT 8
#define NMOM  3
#define H_    256
#define BINSZ 500
#define NBINS 10
#define KNN   16
#define ENCD  26   // NCIN + (F-1)
#define XRD   34   // ENCD + NCOUT
#define M_TOT (B_*N_)  // 40000

typedef unsigned short u16;
typedef _Float16 half8 __attribute__((ext_vector_type(8)));
typedef float f32x4_ __attribute__((ext_vector_type(4)));

__device__ __forceinline__ float elu_f(float x){ return x > 0.f ? x : expm1f(x); }
__device__ __forceinline__ float selu_f(float x){
    const float scale = 1.0507009873554804934193349852946f;
    const float alpha = 1.6732632423543772848170429916717f;
    return x > 0.f ? scale*x : scale*alpha*expm1f(x);
}
__device__ __forceinline__ float sigmoid_f(float x){ return 1.f/(1.f+expf(-x)); }
__device__ __forceinline__ u16 f2h(float x){ _Float16 h = (_Float16)x; return __builtin_bit_cast(u16, h); }
__device__ __forceinline__ float h2f(u16 u){ return (float)__builtin_bit_cast(_Float16, u); }

// ---------------------------------------------------------------- encode (fp32 + padded f16)
__global__ void k_encode(const float* __restrict__ X, float* __restrict__ enc,
                         u16* __restrict__ enc_h){
    int i = blockIdx.x*blockDim.x + threadIdx.x;
    if (i >= M_TOT) return;
    const float* x = X + (size_t)i*F_;
    float* e = enc + (size_t)i*ENCD;
    u16* eh = enc_h + (size_t)i*32;
    int id = (int)x[0];
    #pragma unroll
    for (int c = 0; c < NCIN; ++c){ float v = (c == id) ? 1.f : 0.f; e[c] = v; eh[c] = f2h(v); }
    #pragma unroll
    for (int f = 1; f < F_; ++f){ float v = x[f]; e[NCIN+f-1] = v; eh[NCIN+f-1] = f2h(v); }
    #pragma unroll
    for (int c = ENCD; c < 32; ++c) eh[c] = 0;
}

// ---------------------------------------------------------------- weight prep: [K][256] fp32 -> [256][Ka] f16 (transposed, zero-padded)
struct PrepArgs {
    const float* src[10];
    u16* dst[10];
    int K[10];
    int Ka[10];
    int blk_end[10];   // prefix sums of per-weight block counts (256 elems/block)
};
__global__ void k_prep(PrepArgs a){
    int blk = blockIdx.x;
    int s = 0;
    while (blk >= a.blk_end[s]) s++;
    int base = s ? a.blk_end[s-1] : 0;
    int idx = (blk - base)*256 + threadIdx.x;
    int Ka = a.Ka[s];
    int n = idx / Ka, k = idx % Ka;
    float v = (k < a.K[s]) ? a.src[s][(size_t)k*H_ + n] : 0.f;
    a.dst[s][idx] = f2h(v);
}

// ---------------------------------------------------------------- tiled fp32 GEMM (graph-critical path only)
template<int ACT>
__global__ __launch_bounds__(256) void k_gemm(const float* __restrict__ A,
        const float* __restrict__ W, const float* __restrict__ bias,
        float* __restrict__ C, int M, int K, int Nw){
    __shared__ float As[16][68];
    __shared__ float Bs[16][64];
    int tid = threadIdx.x;
    int tx = tid & 15, ty = tid >> 4;
    int m0 = blockIdx.x * 64, n0 = blockIdx.y * 64;
    float acc[4][4] = {};
    for (int k0 = 0; k0 < K; k0 += 16){
        for (int i = tid; i < 64*16; i += 256){
            int m = i >> 4, k = i & 15;
            float v = 0.f;
            if (k0 + k < K) v = A[(size_t)(m0+m)*K + k0 + k];
            As[k][m] = v;
        }
        for (int i = tid; i < 16*64; i += 256){
            int k = i >> 6, n = i & 63;
            float v = 0.f;
            if (k0 + k < K) v = W[(size_t)(k0+k)*Nw + n0 + n];
            Bs[k][n] = v;
        }
        __syncthreads();
        #pragma unroll
        for (int k = 0; k < 16; ++k){
            float4 a = *(const float4*)&As[k][ty*4];
            float4 b = *(const float4*)&Bs[k][tx*4];
            float av[4] = {a.x,a.y,a.z,a.w};
            float bv[4] = {b.x,b.y,b.z,b.w};
            #pragma unroll
            for (int i2 = 0; i2 < 4; ++i2)
                #pragma unroll
                for (int j = 0; j < 4; ++j)
                    acc[i2][j] += av[i2]*bv[j];
        }
        __syncthreads();
    }
    #pragma unroll
    for (int i2 = 0; i2 < 4; ++i2){
        int m = m0 + ty*4 + i2;
        float o[4];
        #pragma unroll
        for (int j = 0; j < 4; ++j){
            float v = acc[i2][j];
            if (bias) v += bias[n0 + tx*4 + j];
            if (ACT == 1) v = elu_f(v);
            else if (ACT == 2) v = selu_f(v);
            else if (ACT == 3) v = sigmoid_f(v);
            o[j] = v;
        }
        *(float4*)&C[(size_t)m*Nw + n0 + tx*4] = *(float4*)o;
    }
}

// ---------------------------------------------------------------- f16 MFMA GEMM
// C = act(A[M,K]f16 @ Wt[Nw,K]f16^T + bias). K multiple of 32; Nw multiple of 128.
// Writes fp32 Cf and/or f16 Cb (either may be null).
template<int ACT>
__global__ __launch_bounds__(256) void k_gemm_f16(const u16* __restrict__ A,
        const u16* __restrict__ Wt, const float* __restrict__ bias,
        float* __restrict__ Cf, u16* __restrict__ Cb, int M, int K, int Nw){
    __shared__ u16 Als[4][128][8];   // [k-slot][row][8 k] : fragment-order, conflict-free
    __shared__ u16 Bls[4][128][8];
    int tid = threadIdx.x;
    int lane = tid & 63, w = tid >> 6;
    int wr = (w >> 1)*64, wc = (w & 1)*64;
    int m0 = blockIdx.x*128, n0 = blockIdx.y*128;
    int mloc = tid & 127;
    int ksl  = tid >> 7;   // 0/1
    int gmA = m0 + mloc; if (gmA >= M) gmA = M - 1;
    const u16* Arow = A  + (size_t)gmA*K;
    const u16* Brow = Wt + (size_t)(n0 + mloc)*K;
    f32x4_ z = {0.f, 0.f, 0.f, 0.f};
    f32x4_ acc[4][4];
    #pragma unroll
    for (int i = 0; i < 4; ++i)
        #pragma unroll
        for (int j = 0; j < 4; ++j) acc[i][j] = z;
    const int fr = lane & 15, fks = lane >> 4;
    for (int k0 = 0; k0 < K; k0 += 32){
        *(uint4*)(&Als[ksl  ][mloc][0]) = *(const uint4*)(Arow + k0 +      ksl*8);
        *(uint4*)(&Als[ksl+2][mloc][0]) = *(const uint4*)(Arow + k0 + 16 + ksl*8);
        *(uint4*)(&Bls[ksl  ][mloc][0]) = *(const uint4*)(Brow + k0 +      ksl*8);
        *(uint4*)(&Bls[ksl+2][mloc][0]) = *(const uint4*)(Brow + k0 + 16 + ksl*8);
        __syncthreads();
        half8 af[4], bf[4];
        #pragma unroll
        for (int mi = 0; mi < 4; ++mi)
            af[mi] = *reinterpret_cast<const half8*>(&Als[fks][wr + mi*16 + fr][0]);
        #pragma unroll
        for (int ni = 0; ni < 4; ++ni)
            bf[ni] = *reinterpret_cast<const half8*>(&Bls[fks][wc + ni*16 + fr][0]);
        #pragma unroll
        for (int mi = 0; mi < 4; ++mi)
            #pragma unroll
            for (int ni = 0; ni < 4; ++ni)
                acc[mi][ni] = __builtin_amdgcn_mfma_f32_16x16x32_f16(af[mi], bf[ni], acc[mi][ni], 0, 0, 0);
        __syncthreads();
    }
    // epilogue: D row = (lane>>4)*4 + r, col = lane&15 within each 16x16 frag
    #pragma unroll
    for (int ni = 0; ni < 4; ++ni){
        int col = n0 + wc + ni*16 + fr;
        float bv = bias ? bias[col] : 0.f;
        #pragma unroll
        for (int mi = 0; mi < 4; ++mi){
            #pragma unroll
            for (int r = 0; r < 4; ++r){
                int row = m0 + wr + mi*16 + fks*4 + r;
                if (row < M){
                    float v = acc[mi][ni][r] + bv;
                    if (ACT == 2) v = selu_f(v);
                    else if (ACT == 3) v = sigmoid_f(v);
                    if (Cf) Cf[(size_t)row*Nw + col] = v;
                    if (Cb) Cb[(size_t)row*Nw + col] = f2h(v);
                }
            }
        }
    }
}

// ---------------------------------------------------------------- small-N GEMM (f16 A, fp32 W), Nw=8 or 3
__global__ void k_gemm_small(const u16* __restrict__ A, const float* __restrict__ W,
        const float* __restrict__ bias, float* __restrict__ C, int M, int K, int Nw){
    int t = blockIdx.x*blockDim.x + threadIdx.x;
    if (t >= M*Nw) return;
    int m = t / Nw, c = t % Nw;
    const u16* a = A + (size_t)m*K;
    float acc = 0.f;
    for (int k = 0; k < K; k += 8){
        uint4 u = *(const uint4*)(a + k);
        const u16* us = (const u16*)&u;
        #pragma unroll
        for (int j = 0; j < 8; ++j) acc += h2f(us[j]) * W[(k+j)*Nw + c];
    }
    C[t] = acc + bias[c];
}

// ---------------------------------------------------------------- LSH bin assignment
__global__ void k_bins(const float* __restrict__ xd, const float* __restrict__ R,
                       int* __restrict__ bin_idx){
    int i = blockIdx.x*blockDim.x + threadIdx.x;
    if (i >= M_TOT) return;
    const float* p = xd + (size_t)i*H_;
    float mul[NBINS/2] = {0,0,0,0,0};
    for (int k = 0; k < H_; ++k){
        float x = p[k];
        const float* r = R + k*100;           // R is [256,100], use cols 0..4
        #pragma unroll
        for (int j = 0; j < NBINS/2; ++j) mul[j] += x * r[j];
    }
    float best = mul[0]; int bi = 0;
    #pragma unroll
    for (int j = 1; j < NBINS/2; ++j) if (mul[j] > best){ best = mul[j]; bi = j; }
    #pragma unroll
    for (int j = 0; j < NBINS/2; ++j){ float v = -mul[j]; if (v > best){ best = v; bi = NBINS/2 + j; } }
    bin_idx[i] = bi;
}

// ---------------------------------------------------------------- stable counting sort (per batch)
__global__ __launch_bounds__(256) void k_sort(const int* __restrict__ bin_idx,
                                              int* __restrict__ order){
    int b = blockIdx.x;
    const int* bi = bin_idx + b*N_;
    int* ord = order + b*N_;
    __shared__ int cnt[256][NBINS];
    __shared__ int binoff[NBINS];
    int t = threadIdx.x;
    const int CH = (N_ + 255)/256;  // 20
    int lo = t*CH, hi = lo+CH < N_ ? lo+CH : N_;
    for (int j = 0; j < NBINS; ++j) cnt[t][j] = 0;
    for (int n = lo; n < hi; ++n) cnt[t][bi[n]]++;
    __syncthreads();
    if (t < NBINS){
        int run = 0;
        for (int q = 0; q < 256; ++q){ int v = cnt[q][t]; cnt[q][t] = run; run += v; }
        binoff[t] = run;
    }
    __syncthreads();
    if (t == 0){
        int run = 0;
        for (int j = 0; j < NBINS; ++j){ int v = binoff[j]; binoff[j] = run; run += v; }
    }
    __syncthreads();
    for (int n = lo; n < hi; ++n){
        int v = bi[n];
        int pos = binoff[v] + cnt[t][v]++;
        ord[pos] = n;
    }
}

// ---------------------------------------------------------------- squared norms
__global__ void k_sq(const float* __restrict__ xd, float* __restrict__ sq){
    int i = blockIdx.x*blockDim.x + threadIdx.x;
    if (i >= M_TOT) return;
    const float4* p = (const float4*)(xd + (size_t)i*H_);
    float s = 0.f;
    for (int k = 0; k < H_/4; ++k){ float4 v = p[k]; s += v.x*v.x + v.y*v.y + v.z*v.z + v.w*v.w; }
    sq[i] = s;
}

// ---------------------------------------------------------------- distance-matrix GEMM (fp32, graph-critical)
__global__ __launch_bounds__(256) void k_dist(const float* __restrict__ xd,
        const float* __restrict__ sq, const int* __restrict__ order,
        float* __restrict__ dm){
    int binlin = blockIdx.x;           // b*NBINS + bin
    int b = binlin / NBINS;
    int tr = (blockIdx.y >> 3) * 64;
    int tc = (blockIdx.y & 7) * 64;
    const int* ord = order + b*N_ + (binlin % NBINS)*BINSZ;
    __shared__ int ordr[64], ordc[64];
    __shared__ float sqr[64], sqc[64];
    __shared__ float As[16][68];
    __shared__ float Bs[16][64];
    int tid = threadIdx.x;
    if (tid < 64){
        int rr = tr + tid;
        int node = ord[rr < BINSZ ? rr : 0];
        ordr[tid] = node; sqr[tid] = sq[b*N_ + node];
    } else if (tid < 128){
        int cc = tc + tid - 64;
        int node = ord[cc < BINSZ ? cc : 0];
        ordc[tid-64] = node; sqc[tid-64] = sq[b*N_ + node];
    }
    __syncthreads();
    int tx = tid & 15, ty = tid >> 4;
    float acc[4][4] = {};
    for (int k0 = 0; k0 < H_; k0 += 16){
        for (int i = tid; i < 1024; i += 256){
            int m = i >> 4, k = i & 15;
            As[k][m] = xd[((size_t)b*N_ + ordr[m])*H_ + k0 + k];
        }
        for (int i = tid; i < 1024; i += 256){
            int m = i >> 4, k = i & 15;
            Bs[k][m] = xd[((size_t)b*N_ + ordc[m])*H_ + k0 + k];
        }
        __syncthreads();
        #pragma unroll
        for (int k = 0; k < 16; ++k){
            float4 a = *(const float4*)&As[k][ty*4];
            float4 bv4 = *(const float4*)&Bs[k][tx*4];
            float av[4] = {a.x,a.y,a.z,a.w};
            float bv[4] = {bv4.x,bv4.y,bv4.z,bv4.w};
            #pragma unroll
            for (int i2 = 0; i2 < 4; ++i2)
                #pragma unroll
                for (int j = 0; j < 4; ++j)
                    acc[i2][j] += av[i2]*bv[j];
        }
        __syncthreads();
    }
    #pragma unroll
    for (int i2 = 0; i2 < 4; ++i2){
        int r = tr + ty*4 + i2;
        if (r >= BINSZ) continue;
        #pragma unroll
        for (int j = 0; j < 4; ++j){
            int c = tc + tx*4 + j;
            if (c >= BINSZ) continue;
            float d2 = sqr[ty*4+i2] - 2.f*acc[i2][j] + sqc[tx*4+j];
            dm[((size_t)binlin*BINSZ + r)*BINSZ + c] = expf(-0.1f*sqrtf(fmaxf(d2, 1e-6f)));
        }
    }
}

// ---------------------------------------------------------------- top-16 selection, one wave per row
__global__ __launch_bounds__(256) void k_sel(const float* __restrict__ dm,
        const int* __restrict__ order,
        int* __restrict__ nbr_idx, float* __restrict__ nbr_val,
        float* __restrict__ nrm){
    int g = blockIdx.x*4 + (threadIdx.x >> 6);   // global row 0..39999
    int lane = threadIdx.x & 63;
    int b = g / N_, pos = g % N_;
    int bin = pos / BINSZ, r = pos % BINSZ;
    int binlin = b*NBINS + bin;
    const float* row = dm + ((size_t)binlin*BINSZ + r)*BINSZ;
    unsigned long long key[8];
    #pragma unroll
    for (int s = 0; s < 8; ++s){
        int c = lane + s*64;
        key[s] = 0ull;
        if (c < BINSZ){
            unsigned fb = __float_as_uint(row[c]);   // dm > 0 -> monotone bits
            key[s] = ((unsigned long long)fb << 32) | (unsigned)(BINSZ - c);
        }
    }
    float myv = 0.f; int myc = 0;
    for (int rr = 0; rr < KNN; ++rr){
        unsigned long long k2 = key[0];
        #pragma unroll
        for (int s = 1; s < 8; ++s) if (key[s] > k2) k2 = key[s];
        #pragma unroll
        for (int off = 32; off; off >>= 1){
            unsigned long long o = __shfl_xor(k2, off, 64);
            if (o > k2) k2 = o;
        }
        int c = BINSZ - (int)(k2 & 0xffffffffu);
        float v = __uint_as_float((unsigned)(k2 >> 32));
        if (lane == rr){ myv = v; myc = c; }
        if (lane == (c & 63)) key[c >> 6] = 0ull;   // remove winner
    }
    float deg = 0.f;
    #pragma unroll
    for (int rr = 0; rr < KNN; ++rr) deg += __shfl(myv, rr, 64);
    const int* ord = order + b*N_ + bin*BINSZ;
    int node_i = ord[r];
    if (lane < KNN){
        nbr_idx[((size_t)b*N_ + node_i)*KNN + lane] = ord[myc];
        nbr_val[((size_t)b*N_ + node_i)*KNN + lane] = myv;
    }
    if (lane == 0) nrm[b*N_ + node_i] = 1.f/sqrtf(deg + 1e-6f);
}

// ---------------------------------------------------------------- GHConv combine (fp32 in, f16 out)
__global__ __launch_bounds__(256) void k_ghconv(const float* __restrict__ gate,
        const float* __restrict__ het, const float* __restrict__ hom,
        const int* __restrict__ nbr_idx, const float* __restrict__ nbr_val,
        const float* __restrict__ nrm, u16* __restrict__ out){
    int node = blockIdx.x;           // b*N_ + n
    int b = node / N_;
    int t = threadIdx.x;
    __shared__ int nid[KNN];
    __shared__ float nv[KNN];
    if (t < KNN){
        int d = nbr_idx[(size_t)node*KNN + t];
        nid[t] = d;
        nv[t] = nbr_val[(size_t)node*KNN + t] * nrm[b*N_ + d];
    }
    __syncthreads();
    float acc = 0.f;
    #pragma unroll
    for (int k = 0; k < KNN; ++k)
        acc += nv[k] * hom[((size_t)b*N_ + nid[k])*H_ + t];
    float ni = nrm[node];
    float g = gate[(size_t)node*H_ + t];
    float v = g * (ni * acc) + (1.f - g) * het[(size_t)node*H_ + t];
    out[(size_t)node*H_ + t] = f2h(selu_f(v));
}

// ---------------------------------------------------------------- xr concat -> f16 [M][64] zero-padded
__global__ void k_xr(const float* __restrict__ enc, const float* __restrict__ logits,
                     u16* __restrict__ xr_h){
    int i = blockIdx.x*blockDim.x + threadIdx.x;
    if (i >= M_TOT) return;
    const float* e = enc + (size_t)i*ENCD;
    const float* l = logits + (size_t)i*NCOUT;
    u16* x = xr_h + (size_t)i*64;
    #pragma unroll
    for (int j = 0; j < ENCD; ++j) x[j] = f2h(e[j]);
    #pragma unroll
    for (int j = 0; j < NCOUT; ++j) x[ENCD+j] = f2h(l[j]);
    #pragma unroll
    for (int j = XRD; j < 64; ++j) x[j] = 0;
}

// ----------------------------------------------------------------
extern "C" void kernel_launch(void* const* d_in, const int* in_sizes, int n_in,
                              void* d_out, int out_size, void* d_ws, size_t ws_size,
                              hipStream_t stream){
    const float* X        = (const float*)d_in[0];
    const float* ffn1_w   = (const float*)d_in[1];
    const float* ffn1_b   = (const float*)d_in[2];
    const float* ffn2_w   = (const float*)d_in[3];
    const float* ffn2_b   = (const float*)d_in[4];
    const float* R        = (const float*)d_in[5];
    const float* enc_id_w = (const float*)d_in[6];
    const float* enc_id_b = (const float*)d_in[7];
    const float* wt_id    = (const float*)d_in[8];
    const float* bt_id    = (const float*)d_in[9];
    const float* wh_id    = (const float*)d_in[10];
    const float* theta_id = (const float*)d_in[11];
    const float* dec_id_w = (const float*)d_in[12];
    const float* dec_id_b = (const float*)d_in[13];
    const float* out_id_w = (const float*)d_in[14];
    const float* out_id_b = (const float*)d_in[15];
    const float* enc_reg_w= (const float*)d_in[16];
    const float* enc_reg_b= (const float*)d_in[17];
    const float* wt_reg   = (const float*)d_in[18];
    const float* bt_reg   = (const float*)d_in[19];
    const float* wh_reg   = (const float*)d_in[20];
    const float* theta_reg= (const float*)d_in[21];
    const float* dec_reg_w= (const float*)d_in[22];
    const float* dec_reg_b= (const float*)d_in[23];
    const float* out_reg_w= (const float*)d_in[24];
    const float* out_reg_b= (const float*)d_in[25];

    float* out_logits = (float*)d_out;                       // [B,N,8]
    float* out_mom    = (float*)d_out + (size_t)M_TOT*NCOUT; // [B,N,3]

    float* ws = (float*)d_ws;
    size_t o = 0;
    float* enc  = ws + o; o += (size_t)M_TOT*ENCD;       // 1.04M f
    float* bufB = ws + o; o += (size_t)M_TOT*H_;         // x_dist / hom
    float* bufC = ws + o; o += (size_t)M_TOT*H_;         // ffn1-out / dm lo / gate
    float* bufD = ws + o; o += (size_t)M_TOT*H_;         // dm hi / het
    float* sq   = ws + o; o += M_TOT;
    float* nrm  = ws + o; o += M_TOT;
    float* nbrv = ws + o; o += (size_t)M_TOT*KNN;
    int* ibase   = (int*)(ws + o); o += 18*M_TOT/1 *0 + 0;  // ints: 18*M ints
    o += (size_t)18*M_TOT;  // as float-slots (4B each): bin_idx(M) + order(M) + nbr_idx(16M)
    int* bin_idx = ibase;
    int* order   = ibase + M_TOT;
    int* nbr_idx = ibase + 2*M_TOT;
    // f16 region (u16)
    u16* hbase = (u16*)(ws + o);
    size_t ho = 0;
    u16* enc_h = hbase + ho; ho += (size_t)M_TOT*32;
    u16* xr_h  = hbase + ho; ho += (size_t)M_TOT*64;
    u16* hA_h  = hbase + ho; ho += (size_t)M_TOT*H_;   // h0 / h2 / g1
    u16* h1_h  = hbase + ho; ho += (size_t)M_TOT*H_;   // h1 / g0 / g2
    u16* wt_encid  = hbase + ho; ho += 256*32;
    u16* wt_encreg = hbase + ho; ho += 256*64;
    u16* wtb[8];
    for (int i = 0; i < 8; ++i){ wtb[i] = hbase + ho; ho += 256*256; }
    float* dm = bufC;   // 80 MB over bufC+bufD

    // prep args: enc_id(32), enc_reg(64), wt_id, wh_id, theta_id, dec_id, wt_reg, wh_reg, theta_reg, dec_reg
    PrepArgs pa;
    const float* srcs[10] = {enc_id_w, enc_reg_w, wt_id, wh_id, theta_id, dec_id_w,
                             wt_reg, wh_reg, theta_reg, dec_reg_w};
    u16* dsts[10] = {wt_encid, wt_encreg, wtb[0], wtb[1], wtb[2], wtb[3],
                     wtb[4], wtb[5], wtb[6], wtb[7]};
    int Ks[10]  = {ENCD, XRD, H_, H_, H_, H_, H_, H_, H_, H_};
    int Kas[10] = {32, 64, H_, H_, H_, H_, H_, H_, H_, H_};
    int acc_blk = 0;
    for (int i = 0; i < 10; ++i){
        pa.src[i] = srcs[i]; pa.dst[i] = dsts[i]; pa.K[i] = Ks[i]; pa.Ka[i] = Kas[i];
        acc_blk += 256*Kas[i]/256;
        pa.blk_end[i] = acc_blk;
    }

    dim3 b256(256);
    int nb = (M_TOT + 255)/256;
    dim3 gg(625, H_/64);                 // fp32 GEMM grid
    dim3 gh((M_TOT + 127)/128, H_/128);  // f16 MFMA GEMM grid (313, 2)

    k_prep<<<acc_blk, b256, 0, stream>>>(pa);
    k_encode<<<nb, b256, 0, stream>>>(X, enc, enc_h);

    // ---- x_dist chain (fp32, graph-critical)
    k_gemm<1><<<gg, b256, 0, stream>>>(enc,  ffn1_w, ffn1_b, bufC, M_TOT, ENCD, H_);
    k_gemm<0><<<gg, b256, 0, stream>>>(bufC, ffn2_w, ffn2_b, bufB, M_TOT, H_,   H_); // x_dist -> B

    // ---- graph build (fp32)
    k_bins<<<nb, b256, 0, stream>>>(bufB, R, bin_idx);
    k_sort<<<B_, b256, 0, stream>>>(bin_idx, order);
    k_sq<<<nb, b256, 0, stream>>>(bufB, sq);
    k_dist<<<dim3(B_*NBINS, 64), b256, 0, stream>>>(bufB, sq, order, dm);
    k_sel<<<M_TOT/4, b256, 0, stream>>>(dm, order, nbr_idx, nbrv, nrm);

    // ---- id branch (f16 MFMA)
    k_gemm_f16<2><<<gh, b256, 0, stream>>>(enc_h, wt_encid, enc_id_b, nullptr, hA_h, M_TOT, 32, H_);  // h0
    k_gemm_f16<3><<<gh, b256, 0, stream>>>(hA_h, wtb[0], bt_id,  bufC, nullptr, M_TOT, H_, H_);       // gate
    k_gemm_f16<0><<<gh, b256, 0, stream>>>(hA_h, wtb[1], nullptr, bufD, nullptr, M_TOT, H_, H_);      // het
    k_gemm_f16<0><<<gh, b256, 0, stream>>>(hA_h, wtb[2], nullptr, bufB, nullptr, M_TOT, H_, H_);      // hom
    k_ghconv<<<M_TOT, b256, 0, stream>>>(bufC, bufD, bufB, nbr_idx, nbrv, nrm, h1_h);                 // h1
    k_gemm_f16<2><<<gh, b256, 0, stream>>>(h1_h, wtb[3], dec_id_b, nullptr, hA_h, M_TOT, H_, H_);     // h2
    k_gemm_small<<<(M_TOT*NCOUT + 255)/256, b256, 0, stream>>>(hA_h, out_id_w, out_id_b,
                                                               out_logits, M_TOT, H_, NCOUT);

    // ---- reg branch (f16 MFMA)
    k_xr<<<nb, b256, 0, stream>>>(enc, out_logits, xr_h);
    k_gemm_f16<2><<<gh, b256, 0, stream>>>(xr_h, wt_encreg, enc_reg_b, nullptr, h1_h, M_TOT, 64, H_); // g0
    k_gemm_f16<3><<<gh, b256, 0, stream>>>(h1_h, wtb[4], bt_reg, bufC, nullptr, M_TOT, H_, H_);       // gate
    k_gemm_f16<0><<<gh, b256, 0, stream>>>(h1_h, wtb[5], nullptr, bufD, nullptr, M_TOT, H_, H_);      // het
    k_gemm_f16<0><<<gh, b256, 0, stream>>>(h1_h, wtb[6], nullptr, bufB, nullptr, M_TOT, H_, H_);      // hom
    k_ghconv<<<M_TOT, b256, 0, stream>>>(bufC, bufD, bufB, nbr_idx, nbrv, nrm, hA_h);                 // g1
    k_gemm_f16<2><<<gh, b256, 0, stream>>>(hA_h, wtb[7], dec_reg_b, nullptr, h1_h, M_TOT, H_, H_);    // g2
    k_gemm_small<<<(M_TOT*NMOM + 255)/256, b256, 0, stream>>>(h1_h, out_reg_w, out_reg_b,
                                                              out_mom, M_TOT, H_, NMOM);

    (void)in_sizes; (void)n_in; (void)out_size; (void)ws_size;
}

// Round 4
// 900.696 us; speedup vs baseline: 3.8908x; 1.0242x over previous
//
#include <hip/hip_runtime.h>
#include <math.h>

#define B_    8
#define N_    5000
#define F_    15
#define NCIN  12
#define NCOUT 8
#define NMOM  3
#define H_    256
#define BINSZ 500
#define NBINS 10
#define KNN   16
#define ENCD  26   // NCIN + (F-1)
#define XRD   34   // ENCD + NCOUT
#define M_TOT (B_*N_)  // 40000

typedef unsigned short u16;
typedef _Float16 half8 __attribute__((ext_vector_type(8)));
typedef float f32x4_ __attribute__((ext_vector_type(4)));

__device__ __forceinline__ float elu_f(float x){ return x > 0.f ? x : expm1f(x); }
__device__ __forceinline__ float selu_f(float x){
    const float scale = 1.0507009873554804934193349852946f;
    const float alpha = 1.6732632423543772848170429916717f;
    return x > 0.f ? scale*x : scale*alpha*expm1f(x);
}
__device__ __forceinline__ float sigmoid_f(float x){ return 1.f/(1.f+expf(-x)); }
__device__ __forceinline__ u16 f2h(float x){ _Float16 h = (_Float16)x; return __builtin_bit_cast(u16, h); }
__device__ __forceinline__ float h2f(u16 u){ return (float)__builtin_bit_cast(_Float16, u); }

// ---------------------------------------------------------------- encode (fp32 + padded f16)
__global__ void k_encode(const float* __restrict__ X, float* __restrict__ enc,
                         u16* __restrict__ enc_h){
    int i = blockIdx.x*blockDim.x + threadIdx.x;
    if (i >= M_TOT) return;
    const float* x = X + (size_t)i*F_;
    float* e = enc + (size_t)i*ENCD;
    u16* eh = enc_h + (size_t)i*32;
    int id = (int)x[0];
    #pragma unroll
    for (int c = 0; c < NCIN; ++c){ float v = (c == id) ? 1.f : 0.f; e[c] = v; eh[c] = f2h(v); }
    #pragma unroll
    for (int f = 1; f < F_; ++f){ float v = x[f]; e[NCIN+f-1] = v; eh[NCIN+f-1] = f2h(v); }
    #pragma unroll
    for (int c = ENCD; c < 32; ++c) eh[c] = 0;
}

// ---------------------------------------------------------------- weight prep: [K][256] fp32 -> [256][Ka] f16 (transposed, zero-padded)
struct PrepArgs {
    const float* src[10];
    u16* dst[10];
    int K[10];
    int Ka[10];
    int blk_end[10];
};
__global__ void k_prep(PrepArgs a){
    int blk = blockIdx.x;
    int s = 0;
    while (blk >= a.blk_end[s]) s++;
    int base = s ? a.blk_end[s-1] : 0;
    int idx = (blk - base)*256 + threadIdx.x;
    int Ka = a.Ka[s];
    int n = idx / Ka, k = idx % Ka;
    float v = (k < a.K[s]) ? a.src[s][(size_t)k*H_ + n] : 0.f;
    a.dst[s][idx] = f2h(v);
}

// R [256][100] -> Rt [5][256]
__global__ void k_prepR(const float* __restrict__ R, float* __restrict__ Rt){
    int idx = blockIdx.x*256 + threadIdx.x;   // 5 blocks
    int j = idx >> 8, k = idx & 255;
    Rt[j*H_ + k] = R[(size_t)k*100 + j];
}

// ---------------------------------------------------------------- fp32 GEMM 128x128, 8x8 utile
template<int ACT>
__global__ __launch_bounds__(256) void k_gemm128(const float* __restrict__ A,
        const float* __restrict__ W, const float* __restrict__ bias,
        float* __restrict__ C, int M, int K, int Nw){
    __shared__ float As[16][132];
    __shared__ float Bs[16][132];
    int tid = threadIdx.x;
    int tx = tid & 15, ty = (tid >> 4) & 15;
    int m0 = blockIdx.x*128, n0 = blockIdx.y*128;
    float acc[8][8] = {};
    for (int k0 = 0; k0 < K; k0 += 16){
        #pragma unroll
        for (int i = 0; i < 8; ++i){
            int idx = tid + i*256;
            int m = idx >> 4, k = idx & 15;
            int gm = m0 + m; if (gm >= M) gm = M-1;
            As[k][m] = (k0 + k < K) ? A[(size_t)gm*K + k0 + k] : 0.f;
        }
        #pragma unroll
        for (int i = 0; i < 8; ++i){
            int idx = tid + i*256;
            int k = idx >> 7, n = idx & 127;
            Bs[k][n] = (k0 + k < K) ? W[(size_t)(k0+k)*Nw + n0 + n] : 0.f;
        }
        __syncthreads();
        #pragma unroll
        for (int k = 0; k < 16; ++k){
            float4 a0 = *(const float4*)&As[k][ty*4];
            float4 a1 = *(const float4*)&As[k][64 + ty*4];
            float4 b0 = *(const float4*)&Bs[k][tx*4];
            float4 b1 = *(const float4*)&Bs[k][64 + tx*4];
            float av[8] = {a0.x,a0.y,a0.z,a0.w,a1.x,a1.y,a1.z,a1.w};
            float bv[8] = {b0.x,b0.y,b0.z,b0.w,b1.x,b1.y,b1.z,b1.w};
            #pragma unroll
            for (int i2 = 0; i2 < 8; ++i2)
                #pragma unroll
                for (int j = 0; j < 8; ++j)
                    acc[i2][j] += av[i2]*bv[j];
        }
        __syncthreads();
    }
    #pragma unroll
    for (int i2 = 0; i2 < 8; ++i2){
        int m = m0 + (i2 < 4 ? ty*4 + i2 : 64 + ty*4 + (i2-4));
        if (m >= M) continue;
        #pragma unroll
        for (int jh = 0; jh < 2; ++jh){
            float o[4];
            #pragma unroll
            for (int j = 0; j < 4; ++j){
                float v = acc[i2][jh*4+j];
                if (bias) v += bias[n0 + jh*64 + tx*4 + j];
                if (ACT == 1) v = elu_f(v);
                else if (ACT == 2) v = selu_f(v);
                o[j] = v;
            }
            *(float4*)&C[(size_t)m*Nw + n0 + jh*64 + tx*4] = *(float4*)o;
        }
    }
}

// ---------------------------------------------------------------- f16 MFMA GEMM
template<int ACT>
__global__ __launch_bounds__(256) void k_gemm_f16(const u16* __restrict__ A,
        const u16* __restrict__ Wt, const float* __restrict__ bias,
        float* __restrict__ Cf, u16* __restrict__ Cb, int M, int K, int Nw){
    __shared__ u16 Als[4][128][8];
    __shared__ u16 Bls[4][128][8];
    int tid = threadIdx.x;
    int lane = tid & 63, w = tid >> 6;
    int wr = (w >> 1)*64, wc = (w & 1)*64;
    int m0 = blockIdx.x*128, n0 = blockIdx.y*128;
    int mloc = tid & 127;
    int ksl  = tid >> 7;
    int gmA = m0 + mloc; if (gmA >= M) gmA = M - 1;
    const u16* Arow = A  + (size_t)gmA*K;
    const u16* Brow = Wt + (size_t)(n0 + mloc)*K;
    f32x4_ z = {0.f, 0.f, 0.f, 0.f};
    f32x4_ acc[4][4];
    #pragma unroll
    for (int i = 0; i < 4; ++i)
        #pragma unroll
        for (int j = 0; j < 4; ++j) acc[i][j] = z;
    const int fr = lane & 15, fks = lane >> 4;
    for (int k0 = 0; k0 < K; k0 += 32){
        *(uint4*)(&Als[ksl  ][mloc][0]) = *(const uint4*)(Arow + k0 +      ksl*8);
        *(uint4*)(&Als[ksl+2][mloc][0]) = *(const uint4*)(Arow + k0 + 16 + ksl*8);
        *(uint4*)(&Bls[ksl  ][mloc][0]) = *(const uint4*)(Brow + k0 +      ksl*8);
        *(uint4*)(&Bls[ksl+2][mloc][0]) = *(const uint4*)(Brow + k0 + 16 + ksl*8);
        __syncthreads();
        half8 af[4], bf[4];
        #pragma unroll
        for (int mi = 0; mi < 4; ++mi)
            af[mi] = *reinterpret_cast<const half8*>(&Als[fks][wr + mi*16 + fr][0]);
        #pragma unroll
        for (int ni = 0; ni < 4; ++ni)
            bf[ni] = *reinterpret_cast<const half8*>(&Bls[fks][wc + ni*16 + fr][0]);
        #pragma unroll
        for (int mi = 0; mi < 4; ++mi)
            #pragma unroll
            for (int ni = 0; ni < 4; ++ni)
                acc[mi][ni] = __builtin_amdgcn_mfma_f32_16x16x32_f16(af[mi], bf[ni], acc[mi][ni], 0, 0, 0);
        __syncthreads();
    }
    #pragma unroll
    for (int ni = 0; ni < 4; ++ni){
        int col = n0 + wc + ni*16 + fr;
        float bv = bias ? bias[col] : 0.f;
        #pragma unroll
        for (int mi = 0; mi < 4; ++mi){
            #pragma unroll
            for (int r = 0; r < 4; ++r){
                int row = m0 + wr + mi*16 + fks*4 + r;
                if (row < M){
                    float v = acc[mi][ni][r] + bv;
                    if (ACT == 2) v = selu_f(v);
                    else if (ACT == 3) v = sigmoid_f(v);
                    if (Cf) Cf[(size_t)row*Nw + col] = v;
                    if (Cb) Cb[(size_t)row*Nw + col] = f2h(v);
                }
            }
        }
    }
}

// ---------------------------------------------------------------- small-N GEMM (f16 A, fp32 W), Nw=8 or 3
__global__ void k_gemm_small(const u16* __restrict__ A, const float* __restrict__ W,
        const float* __restrict__ bias, float* __restrict__ C, int M, int K, int Nw){
    int t = blockIdx.x*blockDim.x + threadIdx.x;
    if (t >= M*Nw) return;
    int m = t / Nw, c = t % Nw;
    const u16* a = A + (size_t)m*K;
    float acc = 0.f;
    for (int k = 0; k < K; k += 8){
        uint4 u = *(const uint4*)(a + k);
        const u16* us = (const u16*)&u;
        #pragma unroll
        for (int j = 0; j < 8; ++j) acc += h2f(us[j]) * W[(k+j)*Nw + c];
    }
    C[t] = acc + bias[c];
}

// ---------------------------------------------------------------- LSH bin assignment: one wave per row
__global__ __launch_bounds__(256) void k_bins(const float* __restrict__ xd,
        const float* __restrict__ Rt, int* __restrict__ bin_idx){
    int g = blockIdx.x*4 + (threadIdx.x >> 6);
    int lane = threadIdx.x & 63;
    const float4* p = (const float4*)(xd + (size_t)g*H_);
    float4 x = p[lane];
    float acc[5];
    #pragma unroll
    for (int j = 0; j < 5; ++j){
        float4 r = ((const float4*)(Rt + j*H_))[lane];
        acc[j] = x.x*r.x + x.y*r.y + x.z*r.z + x.w*r.w;
    }
    #pragma unroll
    for (int off = 32; off; off >>= 1)
        #pragma unroll
        for (int j = 0; j < 5; ++j) acc[j] += __shfl_xor(acc[j], off, 64);
    if (lane == 0){
        float best = acc[0]; int bi = 0;
        #pragma unroll
        for (int j = 1; j < 5; ++j) if (acc[j] > best){ best = acc[j]; bi = j; }
        #pragma unroll
        for (int j = 0; j < 5; ++j){ float v = -acc[j]; if (v > best){ best = v; bi = 5 + j; } }
        bin_idx[g] = bi;
    }
}

// ---------------------------------------------------------------- stable counting sort (per batch)
__global__ __launch_bounds__(256) void k_sort(const int* __restrict__ bin_idx,
                                              int* __restrict__ order){
    int b = blockIdx.x;
    const int* bi = bin_idx + b*N_;
    int* ord = order + b*N_;
    __shared__ int cnt[256][NBINS];
    __shared__ int binoff[NBINS];
    int t = threadIdx.x;
    const int CH = (N_ + 255)/256;  // 20
    int lo = t*CH, hi = lo+CH < N_ ? lo+CH : N_;
    for (int j = 0; j < NBINS; ++j) cnt[t][j] = 0;
    for (int n = lo; n < hi; ++n) cnt[t][bi[n]]++;
    __syncthreads();
    if (t < NBINS){
        int run = 0;
        for (int q = 0; q < 256; ++q){ int v = cnt[q][t]; cnt[q][t] = run; run += v; }
        binoff[t] = run;
    }
    __syncthreads();
    if (t == 0){
        int run = 0;
        for (int j = 0; j < NBINS; ++j){ int v = binoff[j]; binoff[j] = run; run += v; }
    }
    __syncthreads();
    for (int n = lo; n < hi; ++n){
        int v = bi[n];
        int pos = binoff[v] + cnt[t][v]++;
        ord[pos] = n;
    }
}

// ---------------------------------------------------------------- gather points into bin order + sq (one wave per row)
__global__ __launch_bounds__(256) void k_gather(const float* __restrict__ xd,
        const int* __restrict__ order, float* __restrict__ xg, float* __restrict__ sqg){
    int g = blockIdx.x*4 + (threadIdx.x >> 6);   // gathered row index = b*N + sorted pos
    int lane = threadIdx.x & 63;
    int b = g / N_;
    int node = order[g];
    const float4* src = (const float4*)(xd + ((size_t)b*N_ + node)*H_);
    float4* dst = (float4*)(xg + (size_t)g*H_);
    float4 v = src[lane];
    dst[lane] = v;
    float s = v.x*v.x + v.y*v.y + v.z*v.z + v.w*v.w;
    #pragma unroll
    for (int off = 32; off; off >>= 1) s += __shfl_xor(s, off, 64);
    if (lane == 0) sqg[g] = s;
}

// ---------------------------------------------------------------- distance-matrix GEMM, 128x128 tile, 8x8 utile
__global__ __launch_bounds__(256) void k_dist(const float* __restrict__ xg,
        const float* __restrict__ sqg, float* __restrict__ dm){
    int binlin = blockIdx.x;                       // b*NBINS + bin
    int tr = (blockIdx.y >> 2)*128, tc = (blockIdx.y & 3)*128;
    const float* xb = xg + (size_t)binlin*BINSZ*H_;
    const float* sqb = sqg + binlin*BINSZ;
    __shared__ float As[16][132];
    __shared__ float Bs[16][132];
    __shared__ float sqr[128], sqc[128];
    int tid = threadIdx.x;
    if (tid < 128){ int r = tr + tid; sqr[tid] = sqb[r < BINSZ ? r : BINSZ-1]; }
    else { int c = tc + (tid-128); sqc[tid-128] = sqb[c < BINSZ ? c : BINSZ-1]; }
    int tx = tid & 15, ty = (tid >> 4) & 15;
    float acc[8][8] = {};
    for (int k0 = 0; k0 < H_; k0 += 16){
        #pragma unroll
        for (int pass = 0; pass < 2; ++pass){
            int m = (tid >> 2) + pass*64;
            int k4 = (tid & 3)*4;
            int r = tr + m; if (r >= BINSZ) r = BINSZ-1;
            float4 v = *(const float4*)&xb[(size_t)r*H_ + k0 + k4];
            As[k4  ][m] = v.x; As[k4+1][m] = v.y; As[k4+2][m] = v.z; As[k4+3][m] = v.w;
            int c = tc + m; if (c >= BINSZ) c = BINSZ-1;
            float4 wv = *(const float4*)&xb[(size_t)c*H_ + k0 + k4];
            Bs[k4  ][m] = wv.x; Bs[k4+1][m] = wv.y; Bs[k4+2][m] = wv.z; Bs[k4+3][m] = wv.w;
        }
        __syncthreads();
        #pragma unroll
        for (int k = 0; k < 16; ++k){
            float4 a0 = *(const float4*)&As[k][ty*4];
            float4 a1 = *(const float4*)&As[k][64 + ty*4];
            float4 b0 = *(const float4*)&Bs[k][tx*4];
            float4 b1 = *(const float4*)&Bs[k][64 + tx*4];
            float av[8] = {a0.x,a0.y,a0.z,a0.w,a1.x,a1.y,a1.z,a1.w};
            float bv[8] = {b0.x,b0.y,b0.z,b0.w,b1.x,b1.y,b1.z,b1.w};
            #pragma unroll
            for (int i2 = 0; i2 < 8; ++i2)
                #pragma unroll
                for (int j = 0; j < 8; ++j)
                    acc[i2][j] += av[i2]*bv[j];
        }
        __syncthreads();
    }
    #pragma unroll
    for (int i2 = 0; i2 < 8; ++i2){
        int mm = (i2 < 4 ? ty*4 + i2 : 64 + ty*4 + (i2-4));
        int r = tr + mm;
        if (r >= BINSZ) continue;
        #pragma unroll
        for (int j = 0; j < 8; ++j){
            int nn = (j < 4 ? tx*4 + j : 64 + tx*4 + (j-4));
            int c = tc + nn;
            if (c >= BINSZ){
                continue;
            }
            float d2 = sqr[mm] - 2.f*acc[i2][j] + sqc[nn];
            dm[((size_t)binlin*BINSZ + r)*BINSZ + c] = expf(-0.1f*sqrtf(fmaxf(d2, 1e-6f)));
        }
    }
}

// ---------------------------------------------------------------- top-16 selection, one wave per row
__global__ __launch_bounds__(256) void k_sel(const float* __restrict__ dm,
        const int* __restrict__ order,
        int* __restrict__ nbr_idx, float* __restrict__ nbr_val,
        float* __restrict__ nrm){
    int g = blockIdx.x*4 + (threadIdx.x >> 6);   // global row 0..39999
    int lane = threadIdx.x & 63;
    int b = g / N_, pos = g % N_;
    int bin = pos / BINSZ, r = pos % BINSZ;
    int binlin = b*NBINS + bin;
    const float* row = dm + ((size_t)binlin*BINSZ + r)*BINSZ;
    unsigned long long key[8];
    #pragma unroll
    for (int s = 0; s < 8; ++s){
        int c = lane + s*64;
        key[s] = 0ull;
        if (c < BINSZ){
            unsigned fb = __float_as_uint(row[c]);   // dm > 0 -> monotone bits
            key[s] = ((unsigned long long)fb << 32) | (unsigned)(BINSZ - c);
        }
    }
    float myv = 0.f; int myc = 0;
    for (int rr = 0; rr < KNN; ++rr){
        unsigned long long k2 = key[0];
        #pragma unroll
        for (int s = 1; s < 8; ++s) if (key[s] > k2) k2 = key[s];
        #pragma unroll
        for (int off = 32; off; off >>= 1){
            unsigned long long o = __shfl_xor(k2, off, 64);
            if (o > k2) k2 = o;
        }
        int c = BINSZ - (int)(k2 & 0xffffffffu);
        float v = __uint_as_float((unsigned)(k2 >> 32));
        if (lane == rr){ myv = v; myc = c; }
        if (lane == (c & 63)) key[c >> 6] = 0ull;   // remove winner
    }
    float deg = 0.f;
    #pragma unroll
    for (int rr = 0; rr < KNN; ++rr) deg += __shfl(myv, rr, 64);
    const int* ord = order + b*N_ + bin*BINSZ;
    int node_i = ord[r];
    if (lane < KNN){
        nbr_idx[((size_t)b*N_ + node_i)*KNN + lane] = ord[myc];
        nbr_val[((size_t)b*N_ + node_i)*KNN + lane] = myv;
    }
    if (lane == 0) nrm[b*N_ + node_i] = 1.f/sqrtf(deg + 1e-6f);
}

// ---------------------------------------------------------------- GHConv combine (f16 in, f16 out)
__global__ __launch_bounds__(256) void k_ghconv(const u16* __restrict__ gate,
        const u16* __restrict__ het, const u16* __restrict__ hom,
        const int* __restrict__ nbr_idx, const float* __restrict__ nbr_val,
        const float* __restrict__ nrm, u16* __restrict__ out){
    int node = blockIdx.x;           // b*N_ + n
    int b = node / N_;
    int t = threadIdx.x;
    __shared__ int nid[KNN];
    __shared__ float nv[KNN];
    if (t < KNN){
        int d = nbr_idx[(size_t)node*KNN + t];
        nid[t] = d;
        nv[t] = nbr_val[(size_t)node*KNN + t] * nrm[b*N_ + d];
    }
    __syncthreads();
    float acc = 0.f;
    #pragma unroll
    for (int k = 0; k < KNN; ++k)
        acc += nv[k] * h2f(hom[((size_t)b*N_ + nid[k])*H_ + t]);
    float ni = nrm[node];
    float g = h2f(gate[(size_t)node*H_ + t]);
    float v = g * (ni * acc) + (1.f - g) * h2f(het[(size_t)node*H_ + t]);
    out[(size_t)node*H_ + t] = f2h(selu_f(v));
}

// ---------------------------------------------------------------- xr concat -> f16 [M][64] zero-padded
__global__ void k_xr(const float* __restrict__ enc, const float* __restrict__ logits,
                     u16* __restrict__ xr_h){
    int i = blockIdx.x*blockDim.x + threadIdx.x;
    if (i >= M_TOT) return;
    const float* e = enc + (size_t)i*ENCD;
    const float* l = logits + (size_t)i*NCOUT;
    u16* x = xr_h + (size_t)i*64;
    #pragma unroll
    for (int j = 0; j < ENCD; ++j) x[j] = f2h(e[j]);
    #pragma unroll
    for (int j = 0; j < NCOUT; ++j) x[ENCD+j] = f2h(l[j]);
    #pragma unroll
    for (int j = XRD; j < 64; ++j) x[j] = 0;
}

// ----------------------------------------------------------------
extern "C" void kernel_launch(void* const* d_in, const int* in_sizes, int n_in,
                              void* d_out, int out_size, void* d_ws, size_t ws_size,
                              hipStream_t stream){
    const float* X        = (const float*)d_in[0];
    const float* ffn1_w   = (const float*)d_in[1];
    const float* ffn1_b   = (const float*)d_in[2];
    const float* ffn2_w   = (const float*)d_in[3];
    const float* ffn2_b   = (const float*)d_in[4];
    const float* R        = (const float*)d_in[5];
    const float* enc_id_w = (const float*)d_in[6];
    const float* enc_id_b = (const float*)d_in[7];
    const float* wt_id    = (const float*)d_in[8];
    const float* bt_id    = (const float*)d_in[9];
    const float* wh_id    = (const float*)d_in[10];
    const float* theta_id = (const float*)d_in[11];
    const float* dec_id_w = (const float*)d_in[12];
    const float* dec_id_b = (const float*)d_in[13];
    const float* out_id_w = (const float*)d_in[14];
    const float* out_id_b = (const float*)d_in[15];
    const float* enc_reg_w= (const float*)d_in[16];
    const float* enc_reg_b= (const float*)d_in[17];
    const float* wt_reg   = (const float*)d_in[18];
    const float* bt_reg   = (const float*)d_in[19];
    const float* wh_reg   = (const float*)d_in[20];
    const float* theta_reg= (const float*)d_in[21];
    const float* dec_reg_w= (const float*)d_in[22];
    const float* dec_reg_b= (const float*)d_in[23];
    const float* out_reg_w= (const float*)d_in[24];
    const float* out_reg_b= (const float*)d_in[25];

    float* out_logits = (float*)d_out;                       // [B,N,8]
    float* out_mom    = (float*)d_out + (size_t)M_TOT*NCOUT; // [B,N,3]

    float* ws = (float*)d_ws;
    size_t o = 0;
    float* enc  = ws + o; o += (size_t)M_TOT*ENCD;
    float* bufC = ws + o; o += (size_t)M_TOT*H_;   // ffn1-out -> xg -> gate_h+het_h
    float* bufB = ws + o; o += (size_t)M_TOT*H_;   // x_dist -> dm(part1) -> hom_h
    float* bufD = ws + o; o += (size_t)M_TOT*H_;   // dm(part2)
    float* sqg  = ws + o; o += M_TOT;
    float* nrm  = ws + o; o += M_TOT;
    float* nbrv = ws + o; o += (size_t)M_TOT*KNN;
    float* Rt   = ws + o; o += 5*H_;
    int* ibase   = (int*)(ws + o);
    o += (size_t)18*M_TOT;  // bin_idx(M) + order(M) + nbr_idx(16M) ints
    int* bin_idx = ibase;
    int* order   = ibase + M_TOT;
    int* nbr_idx = ibase + 2*M_TOT;
    // f16 region (u16)
    u16* hbase = (u16*)(ws + o);
    size_t ho = 0;
    u16* enc_h = hbase + ho; ho += (size_t)M_TOT*32;
    u16* xr_h  = hbase + ho; ho += (size_t)M_TOT*64;
    u16* hA_h  = hbase + ho; ho += (size_t)M_TOT*H_;   // h0 / h2 / g1
    u16* h1_h  = hbase + ho; ho += (size_t)M_TOT*H_;   // h1 / g0 / g2
    u16* wt_encid  = hbase + ho; ho += 256*32;
    u16* wt_encreg = hbase + ho; ho += 256*64;
    u16* wtb[8];
    for (int i = 0; i < 8; ++i){ wtb[i] = hbase + ho; ho += 256*256; }
    // aliases into dead regions
    float* xg = bufC;                    // gathered points (41 MB), live bins..dist
    float* dm = bufB;                    // 80 MB spans bufB+bufD, live dist..sel
    u16* gate_h = (u16*)bufC;            // live after sel (xg dead)
    u16* het_h  = gate_h + (size_t)M_TOT*H_;
    u16* hom_h  = (u16*)bufB;            // live after sel (dm dead)

    PrepArgs pa;
    const float* srcs[10] = {enc_id_w, enc_reg_w, wt_id, wh_id, theta_id, dec_id_w,
                             wt_reg, wh_reg, theta_reg, dec_reg_w};
    u16* dsts[10] = {wt_encid, wt_encreg, wtb[0], wtb[1], wtb[2], wtb[3],
                     wtb[4], wtb[5], wtb[6], wtb[7]};
    int Ks[10]  = {ENCD, XRD, H_, H_, H_, H_, H_, H_, H_, H_};
    int Kas[10] = {32, 64, H_, H_, H_, H_, H_, H_, H_, H_};
    int acc_blk = 0;
    for (int i = 0; i < 10; ++i){
        pa.src[i] = srcs[i]; pa.dst[i] = dsts[i]; pa.K[i] = Ks[i]; pa.Ka[i] = Kas[i];
        acc_blk += 256*Kas[i]/256;
        pa.blk_end[i] = acc_blk;
    }

    dim3 b256(256);
    int nb = (M_TOT + 255)/256;
    dim3 gg((M_TOT + 127)/128, H_/128);  // 128^2 fp32 GEMM grid (313, 2)
    dim3 gh((M_TOT + 127)/128, H_/128);  // f16 MFMA GEMM grid (313, 2)

    k_prep<<<acc_blk, b256, 0, stream>>>(pa);
    k_prepR<<<5, b256, 0, stream>>>(R, Rt);
    k_encode<<<nb, b256, 0, stream>>>(X, enc, enc_h);

    // ---- x_dist chain (fp32, graph-critical)
    k_gemm128<1><<<gg, b256, 0, stream>>>(enc,  ffn1_w, ffn1_b, bufC, M_TOT, ENCD, H_);
    k_gemm128<0><<<gg, b256, 0, stream>>>(bufC, ffn2_w, ffn2_b, bufB, M_TOT, H_,   H_); // x_dist -> bufB

    // ---- graph build (fp32)
    k_bins<<<M_TOT/4, b256, 0, stream>>>(bufB, Rt, bin_idx);
    k_sort<<<B_, b256, 0, stream>>>(bin_idx, order);
    k_gather<<<M_TOT/4, b256, 0, stream>>>(bufB, order, xg, sqg);
    k_dist<<<dim3(B_*NBINS, 16), b256, 0, stream>>>(xg, sqg, dm);
    k_sel<<<M_TOT/4, b256, 0, stream>>>(dm, order, nbr_idx, nbrv, nrm);

    // ---- id branch (f16 MFMA)
    k_gemm_f16<2><<<gh, b256, 0, stream>>>(enc_h, wt_encid, enc_id_b, nullptr, hA_h, M_TOT, 32, H_);  // h0
    k_gemm_f16<3><<<gh, b256, 0, stream>>>(hA_h, wtb[0], bt_id,  nullptr, gate_h, M_TOT, H_, H_);     // gate
    k_gemm_f16<0><<<gh, b256, 0, stream>>>(hA_h, wtb[1], nullptr, nullptr, het_h, M_TOT, H_, H_);     // het
    k_gemm_f16<0><<<gh, b256, 0, stream>>>(hA_h, wtb[2], nullptr, nullptr, hom_h, M_TOT, H_, H_);     // hom
    k_ghconv<<<M_TOT, b256, 0, stream>>>(gate_h, het_h, hom_h, nbr_idx, nbrv, nrm, h1_h);             // h1
    k_gemm_f16<2><<<gh, b256, 0, stream>>>(h1_h, wtb[3], dec_id_b, nullptr, hA_h, M_TOT, H_, H_);     // h2
    k_gemm_small<<<(M_TOT*NCOUT + 255)/256, b256, 0, stream>>>(hA_h, out_id_w, out_id_b,
                                                               out_logits, M_TOT, H_, NCOUT);

    // ---- reg branch (f16 MFMA)
    k_xr<<<nb, b256, 0, stream>>>(enc, out_logits, xr_h);
    k_gemm_f16<2><<<gh, b256, 0, stream>>>(xr_h, wt_encreg, enc_reg_b, nullptr, h1_h, M_TOT, 64, H_); // g0
    k_gemm_f16<3><<<gh, b256, 0, stream>>>(h1_h, wtb[4], bt_reg, nullptr, gate_h, M_TOT, H_, H_);     // gate
    k_gemm_f16<0><<<gh, b256, 0, stream>>>(h1_h, wtb[5], nullptr, nullptr, het_h, M_TOT, H_, H_);     // het
    k_gemm_f16<0><<<gh, b256, 0, stream>>>(h1_h, wtb[6], nullptr, nullptr, hom_h, M_TOT, H_, H_);     // hom
    k_ghconv<<<M_TOT, b256, 0, stream>>>(gate_h, het_h, hom_h, nbr_idx, nbrv, nrm, hA_h);             // g1
    k_gemm_f16<2><<<gh, b256, 0, stream>>>(hA_h, wtb[7], dec_reg_b, nullptr, h1_h, M_TOT, H_, H_);    // g2
    k_gemm_small<<<(M_TOT*NMOM + 255)/256, b256, 0, stream>>>(h1_h, out_reg_w, out_reg_b,
                                                              out_mom, M_TOT, H_, NMOM);

    (void)in_sizes; (void)n_in; (void)out_size; (void)ws_size;
}